// Round 2
// baseline (155.151 us; speedup 1.0000x reference)
//
#include <hip/hip_runtime.h>

// Problem constants (GATLayer): B=4, N=2048, TOKEN_DIM=512, HIDDEN=128
// IO dtype: fp32 (reference setup_inputs is jnp.float32; round-1 NaN confirmed
// bf16 misread). Internally: bf16 MFMA with fp32 accumulate.
#define NB      4
#define NTOK    2048
#define TOKDIM  512
#define HID     128
#define NROWS   (NB * NTOK)      // 8192
#define LN_EPS  1e-5f
#define NEG_SLOPE 0.01f

typedef short bf16x8 __attribute__((ext_vector_type(8)));   // 8 bf16 in 4 VGPRs
typedef float f32x4  __attribute__((ext_vector_type(4)));

static __device__ __forceinline__ unsigned short f2bf(float f) {
    union { float f; unsigned int i; } v; v.f = f;
    unsigned int i = v.i;
    i += 0x7FFFu + ((i >> 16) & 1u);   // round-to-nearest-even
    return (unsigned short)(i >> 16);
}

// convert 8 contiguous fp32 -> bf16x8 fragment (two float4 loads)
static __device__ __forceinline__ bf16x8 cvt8(const float* __restrict__ p) {
    float4 a = *(const float4*)(p);
    float4 b = *(const float4*)(p + 4);
    bf16x8 r;
    r[0] = (short)f2bf(a.x); r[1] = (short)f2bf(a.y);
    r[2] = (short)f2bf(a.z); r[3] = (short)f2bf(a.w);
    r[4] = (short)f2bf(b.x); r[5] = (short)f2bf(b.y);
    r[6] = (short)f2bf(b.z); r[7] = (short)f2bf(b.w);
    return r;
}

// ---------------------------------------------------------------------------
// Kernel 1a: h_pre = X @ W^T   (fp32 accumulate via bf16 MFMA)
// X: [8192][512] fp32, W: [128][512] fp32, h_pre: [8192][128] fp32
// Block = 8 waves; wave w owns n-tile [w*16, w*16+16); block owns 16 rows.
// A-frag: A[m=lane&15][k=quad*8+j]  -> 32B contiguous in X row
// B-frag: B[k=quad*8+j][n=lane&15] = W[n][k] -> 32B contiguous in W row
// D: row=(lane>>4)*4+r, col=lane&15
// ---------------------------------------------------------------------------
__global__ __launch_bounds__(512) void k_fc(const float* __restrict__ X,
                                            const float* __restrict__ W,
                                            float* __restrict__ hpre) {
    const int tid  = threadIdx.x;
    const int wv   = tid >> 6;
    const int lane = tid & 63;
    const int m    = lane & 15;
    const int q    = lane >> 4;
    const int rowbase = blockIdx.x * 16;
    const int nbase   = wv * 16;

    const float* xp = X + (size_t)(rowbase + m) * TOKDIM + q * 8;
    const float* wp = W + (size_t)(nbase   + m) * TOKDIM + q * 8;

    f32x4 acc = {0.f, 0.f, 0.f, 0.f};
#pragma unroll
    for (int kk = 0; kk < TOKDIM / 32; ++kk) {
        bf16x8 a = cvt8(xp + kk * 32);
        bf16x8 b = cvt8(wp + kk * 32);
        acc = __builtin_amdgcn_mfma_f32_16x16x32_bf16(a, b, acc, 0, 0, 0);
    }
#pragma unroll
    for (int r = 0; r < 4; ++r) {
        int row = rowbase + q * 4 + r;
        hpre[(size_t)row * HID + nbase + m] = acc[r];
    }
}

// ---------------------------------------------------------------------------
// Kernel 1b: per-row bias + LayerNorm + scores.
// One wave per row (block = 4 waves). Each lane handles 2 columns.
// Outputs: hbf [8192][128] bf16 (LN'd h), srow [8192] fp32, cc [8192] fp32
// where cc = s_col + attn_b.
// ---------------------------------------------------------------------------
__global__ __launch_bounds__(256) void k_ln(const float* __restrict__ hpre,
                                            const float* __restrict__ fcb,
                                            const float* __restrict__ attnw,
                                            const float* __restrict__ attnb,
                                            const float* __restrict__ lng,
                                            const float* __restrict__ lnb,
                                            unsigned short* __restrict__ hbf,
                                            float* __restrict__ srow,
                                            float* __restrict__ cc) {
    const int tid  = threadIdx.x;
    const int wv   = tid >> 6;
    const int lane = tid & 63;
    const int row  = blockIdx.x * 4 + wv;
    const int c0   = lane * 2, c1 = lane * 2 + 1;

    const float* hp = hpre + (size_t)row * HID;
    float v0 = hp[c0] + fcb[c0];
    float v1 = hp[c1] + fcb[c1];

    float s  = v0 + v1;
    float ss = v0 * v0 + v1 * v1;
#pragma unroll
    for (int d = 1; d < 64; d <<= 1) {
        s  += __shfl_xor(s,  d, 64);
        ss += __shfl_xor(ss, d, 64);
    }
    float mu  = s * (1.f / HID);
    float var = ss * (1.f / HID) - mu * mu;
    float rs  = rsqrtf(var + LN_EPS);

    float n0 = lng[c0] * (v0 - mu) * rs + lnb[c0];
    float n1 = lng[c1] * (v1 - mu) * rs + lnb[c1];

    unsigned int packed = ((unsigned int)f2bf(n1) << 16) | (unsigned int)f2bf(n0);
    *(unsigned int*)(hbf + (size_t)row * HID + c0) = packed;

    float sr = n0 * attnw[c0]       + n1 * attnw[c1];
    float sc = n0 * attnw[HID + c0] + n1 * attnw[HID + c1];
#pragma unroll
    for (int d = 1; d < 64; d <<= 1) {
        sr += __shfl_xor(sr, d, 64);
        sc += __shfl_xor(sc, d, 64);
    }
    if (lane == 0) {
        srow[row] = sr;
        cc[row]   = sc + attnb[0];
    }
}

// ---------------------------------------------------------------------------
// Kernel 1c: transpose h -> hT per batch. hbf [b][j][d] -> hT [b][d][j] (bf16)
// 64x64 tiles, LDS staging, 8-byte vector loads/stores on the global side.
// Grid: 4 batches * 32 j-tiles * 2 d-tiles = 256 blocks, 256 threads.
// ---------------------------------------------------------------------------
__global__ __launch_bounds__(256) void k_tr(const unsigned short* __restrict__ hbf,
                                            unsigned short* __restrict__ hT) {
    __shared__ unsigned short tile[64][72];   // +8 pad
    const int bidx = blockIdx.x;
    const int b    = bidx >> 6;
    const int rem  = bidx & 63;
    const int jt   = rem & 31;
    const int dt   = rem >> 5;
    const int tid  = threadIdx.x;

    {
        const int jl = tid >> 2, cg = tid & 3;
        const unsigned short* src =
            hbf + ((size_t)(b * NTOK + jt * 64 + jl)) * HID + dt * 64 + cg * 16;
#pragma unroll
        for (int u = 0; u < 4; ++u) {
            ushort4 v = *(const ushort4*)(src + u * 4);
            *(ushort4*)&tile[jl][cg * 16 + u * 4] = v;
        }
    }
    __syncthreads();
    {
        const int dl = tid >> 2, jg = tid & 3;
        unsigned short* dst =
            hT + ((size_t)(b * HID + dt * 64 + dl)) * NTOK + jt * 64 + jg * 16;
#pragma unroll
        for (int u = 0; u < 4; ++u) {
            ushort4 v;
            v.x = tile[jg * 16 + u * 4 + 0][dl];
            v.y = tile[jg * 16 + u * 4 + 1][dl];
            v.z = tile[jg * 16 + u * 4 + 2][dl];
            v.w = tile[jg * 16 + u * 4 + 3][dl];
            *(ushort4*)(dst + u * 4) = v;
        }
    }
}

// ---------------------------------------------------------------------------
// Kernel 2: attention. For each (b, i-tile of 16): softmax over j (no max
// shift needed: logits ~N(0,0.4^2), exp can't overflow), PV via MFMA with P
// computed in-register. Block = 8 waves; wave w owns d-tile [w*16,+16).
// A-frag(P): lane computes p[m][jt*32 + q*8 + j'] itself (exp fp32 -> bf16).
// B-frag(h): hT[b][dbase + (lane&15)][jt*32 + q*8 + j'] -> 16B contiguous.
// Denominator: fp32 lsum per lane, shuffle-xor 16/32 combine.
// ---------------------------------------------------------------------------
__global__ __launch_bounds__(512) void k_attn(const unsigned short* __restrict__ hT,
                                              const float* __restrict__ srow,
                                              const float* __restrict__ cc,
                                              float* __restrict__ out) {
    const int tid  = threadIdx.x;
    const int wv   = tid >> 6;
    const int lane = tid & 63;
    const int m    = lane & 15;
    const int q    = lane >> 4;
    const int bid  = blockIdx.x;
    const int b    = bid >> 7;        // 128 i-tiles per batch
    const int it   = bid & 127;
    const int ibase = it * 16;
    const int dbase = wv * 16;

    const float cm = cc[b * NTOK + ibase + m];
    const float* rp = srow + b * NTOK + q * 8;
    const unsigned short* hp =
        hT + ((size_t)(b * HID + dbase + m)) * NTOK + q * 8;

    f32x4 acc = {0.f, 0.f, 0.f, 0.f};
    float lsum = 0.f;

#pragma unroll 2
    for (int jt = 0; jt < NTOK / 32; ++jt) {
        float4 r0 = *(const float4*)(rp + jt * 32);
        float4 r1 = *(const float4*)(rp + jt * 32 + 4);
        bf16x8 af;
        float z, p;
        z = cm + r0.x; z = fmaxf(z, NEG_SLOPE * z); p = __expf(z); lsum += p; af[0] = (short)f2bf(p);
        z = cm + r0.y; z = fmaxf(z, NEG_SLOPE * z); p = __expf(z); lsum += p; af[1] = (short)f2bf(p);
        z = cm + r0.z; z = fmaxf(z, NEG_SLOPE * z); p = __expf(z); lsum += p; af[2] = (short)f2bf(p);
        z = cm + r0.w; z = fmaxf(z, NEG_SLOPE * z); p = __expf(z); lsum += p; af[3] = (short)f2bf(p);
        z = cm + r1.x; z = fmaxf(z, NEG_SLOPE * z); p = __expf(z); lsum += p; af[4] = (short)f2bf(p);
        z = cm + r1.y; z = fmaxf(z, NEG_SLOPE * z); p = __expf(z); lsum += p; af[5] = (short)f2bf(p);
        z = cm + r1.z; z = fmaxf(z, NEG_SLOPE * z); p = __expf(z); lsum += p; af[6] = (short)f2bf(p);
        z = cm + r1.w; z = fmaxf(z, NEG_SLOPE * z); p = __expf(z); lsum += p; af[7] = (short)f2bf(p);

        bf16x8 bf = *(const bf16x8*)(hp + jt * 32);
        acc = __builtin_amdgcn_mfma_f32_16x16x32_bf16(af, bf, acc, 0, 0, 0);
    }

    // full row-denominator for row (lane&15): combine the 4 q-groups
    lsum += __shfl_xor(lsum, 16, 64);
    lsum += __shfl_xor(lsum, 32, 64);

#pragma unroll
    for (int r = 0; r < 4; ++r) {
        float l = __shfl(lsum, q * 4 + r, 64);   // lane q*4+r holds l for row q*4+r
        int row = ibase + q * 4 + r;
        out[((size_t)(b * NTOK + row)) * HID + dbase + m] = acc[r] / l;
    }
}

// ---------------------------------------------------------------------------
extern "C" void kernel_launch(void* const* d_in, const int* in_sizes, int n_in,
                              void* d_out, int out_size, void* d_ws, size_t ws_size,
                              hipStream_t stream) {
    const float* X     = (const float*)d_in[0]; // token_embedding [4,2048,512]
    const float* W     = (const float*)d_in[1]; // fc_w [128,512]
    const float* fcb   = (const float*)d_in[2]; // fc_b [128]
    const float* attnw = (const float*)d_in[3]; // attn_w [1,256]
    const float* attnb = (const float*)d_in[4]; // attn_b [1]
    const float* lng   = (const float*)d_in[5]; // ln_g [128]
    const float* lnb   = (const float*)d_in[6]; // ln_b [128]
    float* out = (float*)d_out;                 // h_prime [4,2048,128] fp32

    char* ws = (char*)d_ws;
    // layout: [0,4MB) h_pre fp32 (later reused as hT bf16, 2MB — h_pre dead by then)
    //         [4MB,6MB) hbf bf16; [6MB,+32KB) srow fp32; then cc fp32
    float*          hpre = (float*)ws;
    unsigned short* hT   = (unsigned short*)ws;
    unsigned short* hbf  = (unsigned short*)(ws + 4u * 1024 * 1024);
    float*          srow = (float*)(ws + 6u * 1024 * 1024);
    float*          cchd = (float*)(ws + 6u * 1024 * 1024 + 32u * 1024);

    k_fc  <<<NROWS / 16, 512, 0, stream>>>(X, W, hpre);
    k_ln  <<<NROWS / 4,  256, 0, stream>>>(hpre, fcb, attnw, attnb, lng, lnb, hbf, srow, cchd);
    k_tr  <<<256,        256, 0, stream>>>(hbf, hT);
    k_attn<<<NROWS / 16, 512, 0, stream>>>(hT, srow, cchd, out);
}

// Round 5
// 145.875 us; speedup vs baseline: 1.0636x; 1.0636x over previous
//
#include <hip/hip_runtime.h>

// Problem constants (GATLayer): B=4, N=2048, TOKEN_DIM=512, HIDDEN=128
// IO dtype: fp32. Internally: bf16 MFMA with fp32 accumulate.
// Base: round-2 PASSING kernel. Only change: k_attn computes each exp once
// (8x redundancy removed) by staging A-fragments through LDS as opaque
// 16-byte blobs; grid/fragment/output mappings identical to round 2.
#define NB      4
#define NTOK    2048
#define TOKDIM  512
#define HID     128
#define NROWS   (NB * NTOK)      // 8192
#define LN_EPS  1e-5f
#define NEG_SLOPE 0.01f

typedef short bf16x8 __attribute__((ext_vector_type(8)));   // 8 bf16 in 4 VGPRs
typedef float f32x4  __attribute__((ext_vector_type(4)));

static __device__ __forceinline__ unsigned short f2bf(float f) {
    union { float f; unsigned int i; } v; v.f = f;
    unsigned int i = v.i;
    i += 0x7FFFu + ((i >> 16) & 1u);   // round-to-nearest-even
    return (unsigned short)(i >> 16);
}

// convert 8 contiguous fp32 -> bf16x8 fragment (two float4 loads)
static __device__ __forceinline__ bf16x8 cvt8(const float* __restrict__ p) {
    float4 a = *(const float4*)(p);
    float4 b = *(const float4*)(p + 4);
    bf16x8 r;
    r[0] = (short)f2bf(a.x); r[1] = (short)f2bf(a.y);
    r[2] = (short)f2bf(a.z); r[3] = (short)f2bf(a.w);
    r[4] = (short)f2bf(b.x); r[5] = (short)f2bf(b.y);
    r[6] = (short)f2bf(b.z); r[7] = (short)f2bf(b.w);
    return r;
}

// ---------------------------------------------------------------------------
// Kernel 1a: h_pre = X @ W^T  (identical to round-2 passing version)
// ---------------------------------------------------------------------------
__global__ __launch_bounds__(512) void k_fc(const float* __restrict__ X,
                                            const float* __restrict__ W,
                                            float* __restrict__ hpre) {
    const int tid  = threadIdx.x;
    const int wv   = tid >> 6;
    const int lane = tid & 63;
    const int m    = lane & 15;
    const int q    = lane >> 4;
    const int rowbase = blockIdx.x * 16;
    const int nbase   = wv * 16;

    const float* xp = X + (size_t)(rowbase + m) * TOKDIM + q * 8;
    const float* wp = W + (size_t)(nbase   + m) * TOKDIM + q * 8;

    f32x4 acc = {0.f, 0.f, 0.f, 0.f};
#pragma unroll
    for (int kk = 0; kk < TOKDIM / 32; ++kk) {
        bf16x8 a = cvt8(xp + kk * 32);
        bf16x8 b = cvt8(wp + kk * 32);
        acc = __builtin_amdgcn_mfma_f32_16x16x32_bf16(a, b, acc, 0, 0, 0);
    }
#pragma unroll
    for (int r = 0; r < 4; ++r) {
        int row = rowbase + q * 4 + r;
        hpre[(size_t)row * HID + nbase + m] = acc[r];
    }
}

// ---------------------------------------------------------------------------
// Kernel 1b: bias + LayerNorm + scores (identical to round-2 passing version)
// ---------------------------------------------------------------------------
__global__ __launch_bounds__(256) void k_ln(const float* __restrict__ hpre,
                                            const float* __restrict__ fcb,
                                            const float* __restrict__ attnw,
                                            const float* __restrict__ attnb,
                                            const float* __restrict__ lng,
                                            const float* __restrict__ lnb,
                                            unsigned short* __restrict__ hbf,
                                            float* __restrict__ srow,
                                            float* __restrict__ cc) {
    const int tid  = threadIdx.x;
    const int wv   = tid >> 6;
    const int lane = tid & 63;
    const int row  = blockIdx.x * 4 + wv;
    const int c0   = lane * 2, c1 = lane * 2 + 1;

    const float* hp = hpre + (size_t)row * HID;
    float v0 = hp[c0] + fcb[c0];
    float v1 = hp[c1] + fcb[c1];

    float s  = v0 + v1;
    float ss = v0 * v0 + v1 * v1;
#pragma unroll
    for (int d = 1; d < 64; d <<= 1) {
        s  += __shfl_xor(s,  d, 64);
        ss += __shfl_xor(ss, d, 64);
    }
    float mu  = s * (1.f / HID);
    float var = ss * (1.f / HID) - mu * mu;
    float rs  = rsqrtf(var + LN_EPS);

    float n0 = lng[c0] * (v0 - mu) * rs + lnb[c0];
    float n1 = lng[c1] * (v1 - mu) * rs + lnb[c1];

    unsigned int packed = ((unsigned int)f2bf(n1) << 16) | (unsigned int)f2bf(n0);
    *(unsigned int*)(hbf + (size_t)row * HID + c0) = packed;

    float sr = n0 * attnw[c0]       + n1 * attnw[c1];
    float sc = n0 * attnw[HID + c0] + n1 * attnw[HID + c1];
#pragma unroll
    for (int d = 1; d < 64; d <<= 1) {
        sr += __shfl_xor(sr, d, 64);
        sc += __shfl_xor(sc, d, 64);
    }
    if (lane == 0) {
        srow[row] = sr;
        cc[row]   = sc + attnb[0];
    }
}

// ---------------------------------------------------------------------------
// Kernel 1c: transpose h -> hT per batch (unchanged, round-2 validated)
// ---------------------------------------------------------------------------
__global__ __launch_bounds__(256) void k_tr(const unsigned short* __restrict__ hbf,
                                            unsigned short* __restrict__ hT) {
    __shared__ unsigned short tile[64][72];   // +8 pad
    const int bidx = blockIdx.x;
    const int b    = bidx >> 6;
    const int rem  = bidx & 63;
    const int jt   = rem & 31;
    const int dt   = rem >> 5;
    const int tid  = threadIdx.x;

    {
        const int jl = tid >> 2, cg = tid & 3;
        const unsigned short* src =
            hbf + ((size_t)(b * NTOK + jt * 64 + jl)) * HID + dt * 64 + cg * 16;
#pragma unroll
        for (int u = 0; u < 4; ++u) {
            ushort4 v = *(const ushort4*)(src + u * 4);
            *(ushort4*)&tile[jl][cg * 16 + u * 4] = v;
        }
    }
    __syncthreads();
    {
        const int dl = tid >> 2, jg = tid & 3;
        unsigned short* dst =
            hT + ((size_t)(b * HID + dt * 64 + dl)) * NTOK + jt * 64 + jg * 16;
#pragma unroll
        for (int u = 0; u < 4; ++u) {
            ushort4 v;
            v.x = tile[jg * 16 + u * 4 + 0][dl];
            v.y = tile[jg * 16 + u * 4 + 1][dl];
            v.z = tile[jg * 16 + u * 4 + 2][dl];
            v.w = tile[jg * 16 + u * 4 + 3][dl];
            *(ushort4*)(dst + u * 4) = v;
        }
    }
}

// ---------------------------------------------------------------------------
// Kernel 2 (v4): round-2 structure, exp redundancy removed via LDS staging.
// Grid NROWS/16 = 512 blocks x 512 threads (8 waves), identical to round 2.
// Wave wv owns d-tile [wv*16,+16); all waves consume all j.
// j processed in 8 chunks of 256. Per chunk:
//   produce: wave wv computes the A-frag (16x32 P slice) for j-window
//            ch*256 + wv*32, exactly as round 2 built its frags, and stores
//            the lane's 16-byte frag blob to pbuf[wv][lane].
//   consume: each wave runs 8 MFMA k-steps; step s reads blob pbuf[s][lane]
//            (same j-window as B-frag at hp + ch*256 + s*32 — mapping-safe
//            since blobs are never reinterpreted).
// Denominators: dsum[wv][q][m] partials (each j counted once), summed in
// epilogue. Output mapping identical to round 2.
// ---------------------------------------------------------------------------
__global__ __launch_bounds__(512) void k_attn(const unsigned short* __restrict__ hT,
                                              const float* __restrict__ srow,
                                              const float* __restrict__ cc,
                                              float* __restrict__ out) {
    __shared__ unsigned short pbuf[8][64][8];   // 8 KB: [slice][lane][16B frag]
    __shared__ float dsum[8][4][16];            // 2 KB: [wave][q][m] denom partials

    const int tid  = threadIdx.x;
    const int wv   = tid >> 6;
    const int lane = tid & 63;
    const int m    = lane & 15;
    const int q    = lane >> 4;
    const int bid  = blockIdx.x;
    const int b    = bid >> 7;        // 128 i-tiles per batch
    const int it   = bid & 127;
    const int ibase = it * 16;
    const int dbase = wv * 16;

    const float cm = cc[b * NTOK + ibase + m];
    // producer j-base: this wave covers window wv of each 256-j chunk
    const float* rp = srow + b * NTOK + wv * 32 + q * 8;
    // consumer B pointer: identical to round 2
    const unsigned short* hp =
        hT + ((size_t)(b * HID + dbase + m)) * NTOK + q * 8;

    f32x4 acc = {0.f, 0.f, 0.f, 0.f};
    float lsum = 0.f;

    for (int ch = 0; ch < 8; ++ch) {
        // ---- produce this wave's A-frag for j = ch*256 + wv*32 + q*8 + u
        float4 r0 = *(const float4*)(rp + ch * 256);
        float4 r1 = *(const float4*)(rp + ch * 256 + 4);
        bf16x8 af;
        float z, p;
        z = cm + r0.x; z = fmaxf(z, NEG_SLOPE * z); p = __expf(z); lsum += p; af[0] = (short)f2bf(p);
        z = cm + r0.y; z = fmaxf(z, NEG_SLOPE * z); p = __expf(z); lsum += p; af[1] = (short)f2bf(p);
        z = cm + r0.z; z = fmaxf(z, NEG_SLOPE * z); p = __expf(z); lsum += p; af[2] = (short)f2bf(p);
        z = cm + r0.w; z = fmaxf(z, NEG_SLOPE * z); p = __expf(z); lsum += p; af[3] = (short)f2bf(p);
        z = cm + r1.x; z = fmaxf(z, NEG_SLOPE * z); p = __expf(z); lsum += p; af[4] = (short)f2bf(p);
        z = cm + r1.y; z = fmaxf(z, NEG_SLOPE * z); p = __expf(z); lsum += p; af[5] = (short)f2bf(p);
        z = cm + r1.z; z = fmaxf(z, NEG_SLOPE * z); p = __expf(z); lsum += p; af[6] = (short)f2bf(p);
        z = cm + r1.w; z = fmaxf(z, NEG_SLOPE * z); p = __expf(z); lsum += p; af[7] = (short)f2bf(p);

        *(bf16x8*)&pbuf[wv][lane][0] = af;
        __syncthreads();

        // ---- consume: 8 k-steps; step s pairs blob slice s with B window s
#pragma unroll
        for (int s = 0; s < 8; ++s) {
            bf16x8 a   = *(const bf16x8*)&pbuf[s][lane][0];
            bf16x8 bfr = *(const bf16x8*)(hp + ch * 256 + s * 32);
            acc = __builtin_amdgcn_mfma_f32_16x16x32_bf16(a, bfr, acc, 0, 0, 0);
        }
        __syncthreads();   // protect pbuf before next chunk's overwrite
    }

    // denominator partials: lane (m,q) of wave wv covered row m,
    // j in {ch*256 + wv*32 + q*8 + u} — each j exactly once across (wv,q,u,ch)
    dsum[wv][q][m] = lsum;
    __syncthreads();

    float den[4];
#pragma unroll
    for (int r = 0; r < 4; ++r) {
        int rw = q * 4 + r;
        float d = 0.f;
#pragma unroll
        for (int w2 = 0; w2 < 8; ++w2)
#pragma unroll
            for (int q2 = 0; q2 < 4; ++q2)
                d += dsum[w2][q2][rw];
        den[r] = 1.f / d;
    }

#pragma unroll
    for (int r = 0; r < 4; ++r) {
        int row = ibase + q * 4 + r;
        out[((size_t)(b * NTOK + row)) * HID + dbase + m] = acc[r] * den[r];
    }
}

// ---------------------------------------------------------------------------
extern "C" void kernel_launch(void* const* d_in, const int* in_sizes, int n_in,
                              void* d_out, int out_size, void* d_ws, size_t ws_size,
                              hipStream_t stream) {
    const float* X     = (const float*)d_in[0]; // token_embedding [4,2048,512]
    const float* W     = (const float*)d_in[1]; // fc_w [128,512]
    const float* fcb   = (const float*)d_in[2]; // fc_b [128]
    const float* attnw = (const float*)d_in[3]; // attn_w [1,256]
    const float* attnb = (const float*)d_in[4]; // attn_b [1]
    const float* lng   = (const float*)d_in[5]; // ln_g [128]
    const float* lnb   = (const float*)d_in[6]; // ln_b [128]
    float* out = (float*)d_out;                 // h_prime [4,2048,128] fp32

    char* ws = (char*)d_ws;
    float*          hpre = (float*)ws;                                   // 4 MB
    unsigned short* hT   = (unsigned short*)ws;                          // 2 MB (reuse)
    unsigned short* hbf  = (unsigned short*)(ws + 4u * 1024 * 1024);     // 2 MB
    float*          srow = (float*)(ws + 6u * 1024 * 1024);              // 32 KB
    float*          cchd = (float*)(ws + 6u * 1024 * 1024 + 32u * 1024); // 32 KB

    k_fc  <<<NROWS / 16, 512, 0, stream>>>(X, W, hpre);
    k_ln  <<<NROWS / 4,  256, 0, stream>>>(hpre, fcb, attnw, attnb, lng, lnb, hbf, srow, cchd);
    k_tr  <<<256,        256, 0, stream>>>(hbf, hT);
    k_attn<<<NROWS / 16, 512, 0, stream>>>(hT, srow, cchd, out);
}

// Round 6
// 114.507 us; speedup vs baseline: 1.3550x; 1.2739x over previous
//
#include <hip/hip_runtime.h>

// Problem constants (GATLayer): B=4, N=2048, TOKEN_DIM=512, HIDDEN=128
// IO dtype: fp32. Internally: bf16 MFMA with fp32 accumulate.
// v6 structure: k_cvtw (W->bf16 once) ; k_fused (FC+LN+scores+transpose) ;
// k_attn v5 (P staged in LDS as plain [i][j] matrix, minimal exp work).
// All fp32->bf16 via manual RTNE f2bf (the only packing validated in a
// passing run; pkbf stays benched until isolated).
#define NB      4
#define NTOK    2048
#define TOKDIM  512
#define HID     128
#define NROWS   (NB * NTOK)      // 8192
#define LN_EPS  1e-5f
#define NEG_SLOPE 0.01f

typedef short bf16x8 __attribute__((ext_vector_type(8)));   // 8 bf16 in 4 VGPRs
typedef float f32x4  __attribute__((ext_vector_type(4)));

static __device__ __forceinline__ unsigned short f2bf(float f) {
    union { float f; unsigned int i; } v; v.f = f;
    unsigned int i = v.i;
    i += 0x7FFFu + ((i >> 16) & 1u);   // round-to-nearest-even
    return (unsigned short)(i >> 16);
}

// ---------------------------------------------------------------------------
// k_cvtw: W [128][512] fp32 -> Wbf bf16, once. 64 blocks x 256 thr x 4 elems.
// ---------------------------------------------------------------------------
__global__ __launch_bounds__(256) void k_cvtw(const float* __restrict__ W,
                                              unsigned short* __restrict__ Wbf) {
    const int g = (blockIdx.x * 256 + threadIdx.x) * 4;
    float4 v = *(const float4*)(W + g);
    ushort4 o;
    o.x = f2bf(v.x); o.y = f2bf(v.y); o.z = f2bf(v.z); o.w = f2bf(v.w);
    *(ushort4*)(Wbf + g) = o;
}

// ---------------------------------------------------------------------------
// k_fused: per 16-row tile: FC (MFMA, A from LDS-staged bf16 X, B from Wbf)
//          + bias + LayerNorm + attention scores + transposed hT write.
// Grid 512 blocks x 512 thr (8 waves). Wave wv owns n-cols [wv*16,+16).
// LDS: ldsX[16][520] bf16 (X tile, +8 pad) -> reused as ldsT[128][20] bf16;
//      hfull[16][132] fp32.
// Outputs: hT [b][d][j] bf16, srow [8192] fp32, cc [8192] fp32 (= s_col+b).
// ---------------------------------------------------------------------------
__global__ __launch_bounds__(512) void k_fused(const float* __restrict__ X,
                                               const unsigned short* __restrict__ Wbf,
                                               const float* __restrict__ fcb,
                                               const float* __restrict__ attnw,
                                               const float* __restrict__ attnb,
                                               const float* __restrict__ lng,
                                               const float* __restrict__ lnb,
                                               unsigned short* __restrict__ hT,
                                               float* __restrict__ srow,
                                               float* __restrict__ cc) {
    __shared__ char smem[16640 + 16 * 132 * 4];
    unsigned short* ldsX = (unsigned short*)smem;            // [16][520]
    unsigned short* ldsT = (unsigned short*)smem;            // [128][20] (reuse)
    float* hfull = (float*)(smem + 16640);                   // [16][132]

    const int tid  = threadIdx.x;
    const int wv   = tid >> 6;
    const int lane = tid & 63;
    const int m    = lane & 15;
    const int q    = lane >> 4;
    const int rowbase = blockIdx.x * 16;
    const int nbase   = wv * 16;

    // ---- phase A: stage X tile -> LDS bf16 (each element converted once)
    {
        const int r  = tid >> 5;            // 0..15
        const int c0 = (tid & 31) * 16;     // 0..496
        const float* xp = X + (size_t)(rowbase + r) * TOKDIM + c0;
        bf16x8 v0, v1;
#pragma unroll
        for (int u = 0; u < 8; ++u) v0[u] = (short)f2bf(xp[u]);
#pragma unroll
        for (int u = 0; u < 8; ++u) v1[u] = (short)f2bf(xp[8 + u]);
        *(bf16x8*)&ldsX[r * 520 + c0]     = v0;
        *(bf16x8*)&ldsX[r * 520 + c0 + 8] = v1;
    }
    __syncthreads();

    // ---- phase B: MFMA. A[m][k] from ldsX, B[k][n]=W[n][k] from Wbf.
    const unsigned short* wp = Wbf + (size_t)(nbase + m) * TOKDIM + q * 8;
    f32x4 acc = {0.f, 0.f, 0.f, 0.f};
#pragma unroll
    for (int kk = 0; kk < TOKDIM / 32; ++kk) {
        bf16x8 a = *(const bf16x8*)&ldsX[m * 520 + kk * 32 + q * 8];
        bf16x8 b = *(const bf16x8*)(wp + kk * 32);
        acc = __builtin_amdgcn_mfma_f32_16x16x32_bf16(a, b, acc, 0, 0, 0);
    }

    // ---- phase C: acc (+fc_b) -> hfull LDS
    {
        const float bias = fcb[nbase + m];
#pragma unroll
        for (int r = 0; r < 4; ++r)
            hfull[(q * 4 + r) * 132 + nbase + m] = acc[r] + bias;
    }
    __syncthreads();   // hfull ready; ldsX dead (safe to reuse as ldsT)

    // ---- phase D: LN + scores; write bf16 h into ldsT transposed
    {
        const int r   = tid >> 5;           // row 0..15
        const int l32 = tid & 31;
        const int c0  = l32 * 4;
        float4 hv = *(const float4*)&hfull[r * 132 + c0];
        float v[4] = {hv.x, hv.y, hv.z, hv.w};

        float s  = v[0] + v[1] + v[2] + v[3];
        float ss = v[0]*v[0] + v[1]*v[1] + v[2]*v[2] + v[3]*v[3];
#pragma unroll
        for (int d = 1; d < 32; d <<= 1) {
            s  += __shfl_xor(s,  d, 64);
            ss += __shfl_xor(ss, d, 64);
        }
        float mu  = s * (1.f / HID);
        float var = ss * (1.f / HID) - mu * mu;
        float rs  = rsqrtf(var + LN_EPS);

        float n[4], sr = 0.f, sc = 0.f;
#pragma unroll
        for (int k = 0; k < 4; ++k) {
            n[k] = lng[c0 + k] * (v[k] - mu) * rs + lnb[c0 + k];
            sr += n[k] * attnw[c0 + k];
            sc += n[k] * attnw[HID + c0 + k];
            ldsT[(c0 + k) * 20 + r] = f2bf(n[k]);
        }
#pragma unroll
        for (int d = 1; d < 32; d <<= 1) {
            sr += __shfl_xor(sr, d, 64);
            sc += __shfl_xor(sc, d, 64);
        }
        if (l32 == 0) {
            int grow = rowbase + r;
            srow[grow] = sr;
            cc[grow]   = sc + attnb[0];
        }
    }
    __syncthreads();

    // ---- phase E: coalesced hT write. thread t: d = t>>2, 4 j's.
    {
        const int d  = tid >> 2;
        const int j4 = (tid & 3) * 4;
        const int b    = blockIdx.x >> 7;          // 128 blocks per batch
        const int jblk = (blockIdx.x & 127) * 16;
        ushort4 o;
        o.x = ldsT[d * 20 + j4 + 0];
        o.y = ldsT[d * 20 + j4 + 1];
        o.z = ldsT[d * 20 + j4 + 2];
        o.w = ldsT[d * 20 + j4 + 3];
        *(ushort4*)(hT + ((size_t)(b * HID + d)) * NTOK + jblk + j4) = o;
    }
}

// ---------------------------------------------------------------------------
// k_attn v5: 256 blocks x 512 thr (8 waves); block owns 32 i-rows; j in 8
// chunks of 256. P staged in LDS as a plain bf16 matrix pP[32][264] — no
// cross-wave numerator reduction (each acc lives in ONE wave for all j).
//   produce: thread t -> i_loc=t>>4, jseg=(t&15)*16: 16 exps -> pP row.
//   consume: wave wv owns d-tile [wv*16,+16); per k-step s: one B-frag
//            (global hT), two A-frags (pP rows m / 16+m), 2 MFMAs.
// Denominators: per-thread register partial -> pDen -> denv. No max-shift
// needed (logits ~N(0,0.4^2), exp overflow-safe).
// ---------------------------------------------------------------------------
__global__ __launch_bounds__(512) void k_attn(const unsigned short* __restrict__ hT,
                                              const float* __restrict__ srow,
                                              const float* __restrict__ cc,
                                              float* __restrict__ out) {
    __shared__ unsigned short pP[32][264];   // 16896 B, +8 pad
    __shared__ float pDen[32][16];           // 2 KB
    __shared__ float denv[32];

    const int tid  = threadIdx.x;
    const int wv   = tid >> 6;
    const int lane = tid & 63;
    const int m    = lane & 15;
    const int q    = lane >> 4;
    const int rowbase = blockIdx.x * 32;     // global row base
    const int b    = blockIdx.x >> 6;        // 64 blocks per batch
    const int dbase = wv * 16;

    // producer indices
    const int i_loc = tid >> 4;              // 0..31
    const int jseg  = (tid & 15) * 16;       // 0..240
    const float ci  = cc[rowbase + i_loc];
    const float* sp = srow + (size_t)b * NTOK + jseg;

    // consumer B pointer
    const unsigned short* hp =
        hT + ((size_t)(b * HID + dbase + m)) * NTOK + q * 8;

    f32x4 acc0 = {0.f, 0.f, 0.f, 0.f};      // i-subtile 0 (rows 0..15)
    f32x4 acc1 = {0.f, 0.f, 0.f, 0.f};      // i-subtile 1 (rows 16..31)
    float lsum = 0.f;

    for (int ch = 0; ch < 8; ++ch) {
        // ---- produce: 16 exps -> pP[i_loc][jseg..jseg+16)
        {
            const float* s0 = sp + ch * 256;
            bf16x8 v0, v1;
#pragma unroll
            for (int u = 0; u < 8; ++u) {
                float z = ci + s0[u];
                z = fmaxf(z, NEG_SLOPE * z);
                float p = __expf(z);
                lsum += p;
                v0[u] = (short)f2bf(p);
            }
#pragma unroll
            for (int u = 0; u < 8; ++u) {
                float z = ci + s0[8 + u];
                z = fmaxf(z, NEG_SLOPE * z);
                float p = __expf(z);
                lsum += p;
                v1[u] = (short)f2bf(p);
            }
            *(bf16x8*)&pP[i_loc][jseg]     = v0;
            *(bf16x8*)&pP[i_loc][jseg + 8] = v1;
        }
        __syncthreads();

        // ---- consume: 8 k-steps, B-frag reused by both i-subtiles
#pragma unroll
        for (int s = 0; s < 8; ++s) {
            bf16x8 bfr = *(const bf16x8*)(hp + ch * 256 + s * 32);
            bf16x8 a0  = *(const bf16x8*)&pP[m][s * 32 + q * 8];
            bf16x8 a1  = *(const bf16x8*)&pP[16 + m][s * 32 + q * 8];
            acc0 = __builtin_amdgcn_mfma_f32_16x16x32_bf16(a0, bfr, acc0, 0, 0, 0);
            acc1 = __builtin_amdgcn_mfma_f32_16x16x32_bf16(a1, bfr, acc1, 0, 0, 0);
        }
        __syncthreads();   // protect pP before next produce
    }

    // ---- denominators: thread covered (i_loc, jseg window) across chunks
    pDen[i_loc][tid & 15] = lsum;
    __syncthreads();
    if (tid < 32) {
        float d = 0.f;
#pragma unroll
        for (int k = 0; k < 16; ++k) d += pDen[tid][k];
        denv[tid] = 1.f / d;
    }
    __syncthreads();

    // ---- epilogue: out[row=i][col=d], same validated C/D mapping
#pragma unroll
    for (int r = 0; r < 4; ++r) {
        int r0 = q * 4 + r;
        out[(size_t)(rowbase + r0) * HID + dbase + m]      = acc0[r] * denv[r0];
        out[(size_t)(rowbase + 16 + r0) * HID + dbase + m] = acc1[r] * denv[16 + r0];
    }
}

// ---------------------------------------------------------------------------
extern "C" void kernel_launch(void* const* d_in, const int* in_sizes, int n_in,
                              void* d_out, int out_size, void* d_ws, size_t ws_size,
                              hipStream_t stream) {
    const float* X     = (const float*)d_in[0]; // token_embedding [4,2048,512]
    const float* W     = (const float*)d_in[1]; // fc_w [128,512]
    const float* fcb   = (const float*)d_in[2]; // fc_b [128]
    const float* attnw = (const float*)d_in[3]; // attn_w [1,256]
    const float* attnb = (const float*)d_in[4]; // attn_b [1]
    const float* lng   = (const float*)d_in[5]; // ln_g [128]
    const float* lnb   = (const float*)d_in[6]; // ln_b [128]
    float* out = (float*)d_out;                 // h_prime [4,2048,128] fp32

    char* ws = (char*)d_ws;
    unsigned short* hT   = (unsigned short*)ws;                          // 2 MB
    float*          srow = (float*)(ws + 2u * 1024 * 1024);              // 32 KB
    float*          cchd = (float*)(ws + 2u * 1024 * 1024 + 32u * 1024); // 32 KB
    unsigned short* Wbf  = (unsigned short*)(ws + 2u * 1024 * 1024 + 64u * 1024); // 128 KB

    k_cvtw <<<64,  256, 0, stream>>>(W, Wbf);
    k_fused<<<NROWS / 16, 512, 0, stream>>>(X, Wbf, fcb, attnw, attnb, lng, lnb,
                                            hT, srow, cchd);
    k_attn <<<NROWS / 32, 512, 0, stream>>>(hT, srow, cchd, out);
}

// Round 7
// 110.191 us; speedup vs baseline: 1.4080x; 1.0392x over previous
//
#include <hip/hip_runtime.h>

// Problem constants (GATLayer): B=4, N=2048, TOKEN_DIM=512, HIDDEN=128
// IO dtype: fp32. Internally: bf16 MFMA with fp32 accumulate.
// v7: two dispatches.
//   k_fused: FC(MFMA) + bias + LN + scores + transposed hT  (W cvt inline)
//   k_attn v6: double-buffered P staging, ONE barrier per chunk, explicit
//              register prefetch of srow + B-frags to overlap L2 latency.
// All fp32->bf16 via manual RTNE f2bf (validated in passing runs).
#define NB      4
#define NTOK    2048
#define TOKDIM  512
#define HID     128
#define NROWS   (NB * NTOK)      // 8192
#define LN_EPS  1e-5f
#define NEG_SLOPE 0.01f

typedef short bf16x8 __attribute__((ext_vector_type(8)));   // 8 bf16 in 4 VGPRs
typedef float f32x4  __attribute__((ext_vector_type(4)));

static __device__ __forceinline__ unsigned short f2bf(float f) {
    union { float f; unsigned int i; } v; v.f = f;
    unsigned int i = v.i;
    i += 0x7FFFu + ((i >> 16) & 1u);   // round-to-nearest-even
    return (unsigned short)(i >> 16);
}

// convert 8 contiguous fp32 -> bf16x8 fragment (two float4 loads) [R2-validated]
static __device__ __forceinline__ bf16x8 cvt8(const float* __restrict__ p) {
    float4 a = *(const float4*)(p);
    float4 b = *(const float4*)(p + 4);
    bf16x8 r;
    r[0] = (short)f2bf(a.x); r[1] = (short)f2bf(a.y);
    r[2] = (short)f2bf(a.z); r[3] = (short)f2bf(a.w);
    r[4] = (short)f2bf(b.x); r[5] = (short)f2bf(b.y);
    r[6] = (short)f2bf(b.z); r[7] = (short)f2bf(b.w);
    return r;
}

// ---------------------------------------------------------------------------
// k_fused: per 16-row tile: FC (MFMA, A from LDS-staged bf16 X, B from fp32 W
// converted inline) + bias + LayerNorm + scores + transposed hT write.
// Grid 512 blocks x 512 thr (8 waves). Wave wv owns n-cols [wv*16,+16).
// ---------------------------------------------------------------------------
__global__ __launch_bounds__(512) void k_fused(const float* __restrict__ X,
                                               const float* __restrict__ W,
                                               const float* __restrict__ fcb,
                                               const float* __restrict__ attnw,
                                               const float* __restrict__ attnb,
                                               const float* __restrict__ lng,
                                               const float* __restrict__ lnb,
                                               unsigned short* __restrict__ hT,
                                               float* __restrict__ srow,
                                               float* __restrict__ cc) {
    __shared__ char smem[16640 + 16 * 132 * 4];
    unsigned short* ldsX = (unsigned short*)smem;            // [16][520]
    unsigned short* ldsT = (unsigned short*)smem;            // [128][20] (reuse)
    float* hfull = (float*)(smem + 16640);                   // [16][132]

    const int tid  = threadIdx.x;
    const int wv   = tid >> 6;
    const int lane = tid & 63;
    const int m    = lane & 15;
    const int q    = lane >> 4;
    const int rowbase = blockIdx.x * 16;
    const int nbase   = wv * 16;

    // ---- phase A: stage X tile -> LDS bf16 (each element converted once)
    {
        const int r  = tid >> 5;            // 0..15
        const int c0 = (tid & 31) * 16;     // 0..496
        const float* xp = X + (size_t)(rowbase + r) * TOKDIM + c0;
        bf16x8 v0, v1;
#pragma unroll
        for (int u = 0; u < 8; ++u) v0[u] = (short)f2bf(xp[u]);
#pragma unroll
        for (int u = 0; u < 8; ++u) v1[u] = (short)f2bf(xp[8 + u]);
        *(bf16x8*)&ldsX[r * 520 + c0]     = v0;
        *(bf16x8*)&ldsX[r * 520 + c0 + 8] = v1;
    }
    __syncthreads();

    // ---- phase B: MFMA. A[m][k] from ldsX, B[k][n]=W[n][k] from fp32 W.
    const float* wp = W + (size_t)(nbase + m) * TOKDIM + q * 8;
    f32x4 acc = {0.f, 0.f, 0.f, 0.f};
#pragma unroll
    for (int kk = 0; kk < TOKDIM / 32; ++kk) {
        bf16x8 a = *(const bf16x8*)&ldsX[m * 520 + kk * 32 + q * 8];
        bf16x8 b = cvt8(wp + kk * 32);
        acc = __builtin_amdgcn_mfma_f32_16x16x32_bf16(a, b, acc, 0, 0, 0);
    }

    // ---- phase C: acc (+fc_b) -> hfull LDS
    {
        const float bias = fcb[nbase + m];
#pragma unroll
        for (int r = 0; r < 4; ++r)
            hfull[(q * 4 + r) * 132 + nbase + m] = acc[r] + bias;
    }
    __syncthreads();   // hfull ready; ldsX dead (safe to reuse as ldsT)

    // ---- phase D: LN + scores; write bf16 h into ldsT transposed
    {
        const int r   = tid >> 5;           // row 0..15
        const int l32 = tid & 31;
        const int c0  = l32 * 4;
        float4 hv = *(const float4*)&hfull[r * 132 + c0];
        float v[4] = {hv.x, hv.y, hv.z, hv.w};

        float s  = v[0] + v[1] + v[2] + v[3];
        float ss = v[0]*v[0] + v[1]*v[1] + v[2]*v[2] + v[3]*v[3];
#pragma unroll
        for (int d = 1; d < 32; d <<= 1) {
            s  += __shfl_xor(s,  d, 64);
            ss += __shfl_xor(ss, d, 64);
        }
        float mu  = s * (1.f / HID);
        float var = ss * (1.f / HID) - mu * mu;
        float rs  = rsqrtf(var + LN_EPS);

        float n[4], sr = 0.f, sc = 0.f;
#pragma unroll
        for (int k = 0; k < 4; ++k) {
            n[k] = lng[c0 + k] * (v[k] - mu) * rs + lnb[c0 + k];
            sr += n[k] * attnw[c0 + k];
            sc += n[k] * attnw[HID + c0 + k];
            ldsT[(c0 + k) * 20 + r] = f2bf(n[k]);
        }
#pragma unroll
        for (int d = 1; d < 32; d <<= 1) {
            sr += __shfl_xor(sr, d, 64);
            sc += __shfl_xor(sc, d, 64);
        }
        if (l32 == 0) {
            int grow = rowbase + r;
            srow[grow] = sr;
            cc[grow]   = sc + attnb[0];
        }
    }
    __syncthreads();

    // ---- phase E: coalesced hT write. thread t: d = t>>2, 4 j's.
    {
        const int d  = tid >> 2;
        const int j4 = (tid & 3) * 4;
        const int b    = blockIdx.x >> 7;          // 128 blocks per batch
        const int jblk = (blockIdx.x & 127) * 16;
        ushort4 o;
        o.x = ldsT[d * 20 + j4 + 0];
        o.y = ldsT[d * 20 + j4 + 1];
        o.z = ldsT[d * 20 + j4 + 2];
        o.w = ldsT[d * 20 + j4 + 3];
        *(ushort4*)(hT + ((size_t)(b * HID + d)) * NTOK + jblk + j4) = o;
    }
}

// ---------------------------------------------------------------------------
// k_attn v6: 256 blocks x 512 thr (8 waves); block owns 32 i-rows; j in 8
// chunks of 256. Same mappings as validated v5; pipelining changes only:
//  - pP double-buffered -> ONE barrier per chunk (WAR safe: produce(ch+2)
//    into buf[ch&1] is after barrier(ch+1), consume(ch) is before it).
//  - next chunk's srow (4xfloat4) and all 8 B-frags prefetched into registers
//    BEFORE the barrier, overlapping L2 latency with exp production.
// ---------------------------------------------------------------------------
__global__ __launch_bounds__(512) void k_attn(const unsigned short* __restrict__ hT,
                                              const float* __restrict__ srow,
                                              const float* __restrict__ cc,
                                              float* __restrict__ out) {
    __shared__ unsigned short pP[2][32][264];   // 2 x 16896 B, +8 pad
    __shared__ float pDen[32][16];              // 2 KB
    __shared__ float denv[32];

    const int tid  = threadIdx.x;
    const int wv   = tid >> 6;
    const int lane = tid & 63;
    const int m    = lane & 15;
    const int q    = lane >> 4;
    const int rowbase = blockIdx.x * 32;     // global row base
    const int b    = blockIdx.x >> 6;        // 64 blocks per batch
    const int dbase = wv * 16;

    // producer indices
    const int i_loc = tid >> 4;              // 0..31
    const int jseg  = (tid & 15) * 16;       // 0..240
    const float ci  = cc[rowbase + i_loc];
    const float* sp = srow + (size_t)b * NTOK + jseg;

    // consumer B pointer
    const unsigned short* hp =
        hT + ((size_t)(b * HID + dbase + m)) * NTOK + q * 8;

    f32x4 acc0 = {0.f, 0.f, 0.f, 0.f};      // i-subtile 0 (rows 0..15)
    f32x4 acc1 = {0.f, 0.f, 0.f, 0.f};      // i-subtile 1 (rows 16..31)
    float lsum = 0.f;

    // ---- prefetch chunk 0
    float4 s0 = *(const float4*)(sp);
    float4 s1 = *(const float4*)(sp + 4);
    float4 s2 = *(const float4*)(sp + 8);
    float4 s3 = *(const float4*)(sp + 12);
    bf16x8 bcur[8], bnxt[8];
#pragma unroll
    for (int s = 0; s < 8; ++s) bcur[s] = *(const bf16x8*)(hp + s * 32);

#pragma unroll
    for (int ch = 0; ch < 8; ++ch) {
        // ---- produce chunk ch from prefetched srow values
        {
            float sv[16] = {s0.x, s0.y, s0.z, s0.w, s1.x, s1.y, s1.z, s1.w,
                            s2.x, s2.y, s2.z, s2.w, s3.x, s3.y, s3.z, s3.w};
            bf16x8 v0, v1;
#pragma unroll
            for (int u = 0; u < 8; ++u) {
                float z = ci + sv[u];
                z = fmaxf(z, NEG_SLOPE * z);
                float p = __expf(z);
                lsum += p;
                v0[u] = (short)f2bf(p);
            }
#pragma unroll
            for (int u = 0; u < 8; ++u) {
                float z = ci + sv[8 + u];
                z = fmaxf(z, NEG_SLOPE * z);
                float p = __expf(z);
                lsum += p;
                v1[u] = (short)f2bf(p);
            }
            *(bf16x8*)&pP[ch & 1][i_loc][jseg]     = v0;
            *(bf16x8*)&pP[ch & 1][i_loc][jseg + 8] = v1;
        }

        // ---- prefetch chunk ch+1 (overlaps with barrier + consume below)
        if (ch < 7) {
            const float* spn = sp + (ch + 1) * 256;
            s0 = *(const float4*)(spn);
            s1 = *(const float4*)(spn + 4);
            s2 = *(const float4*)(spn + 8);
            s3 = *(const float4*)(spn + 12);
            const unsigned short* hpn = hp + (ch + 1) * 256;
#pragma unroll
            for (int s = 0; s < 8; ++s) bnxt[s] = *(const bf16x8*)(hpn + s * 32);
        }

        __syncthreads();   // pP[ch&1] ready for all threads

        // ---- consume chunk ch: 8 k-steps, B-frag reused by both i-subtiles
#pragma unroll
        for (int s = 0; s < 8; ++s) {
            bf16x8 a0 = *(const bf16x8*)&pP[ch & 1][m][s * 32 + q * 8];
            bf16x8 a1 = *(const bf16x8*)&pP[ch & 1][16 + m][s * 32 + q * 8];
            acc0 = __builtin_amdgcn_mfma_f32_16x16x32_bf16(a0, bcur[s], acc0, 0, 0, 0);
            acc1 = __builtin_amdgcn_mfma_f32_16x16x32_bf16(a1, bcur[s], acc1, 0, 0, 0);
        }

#pragma unroll
        for (int s = 0; s < 8; ++s) bcur[s] = bnxt[s];
    }

    // ---- denominators: thread covered (i_loc, jseg window) across chunks
    pDen[i_loc][tid & 15] = lsum;
    __syncthreads();
    if (tid < 32) {
        float d = 0.f;
#pragma unroll
        for (int k = 0; k < 16; ++k) d += pDen[tid][k];
        denv[tid] = 1.f / d;
    }
    __syncthreads();

    // ---- epilogue: out[row=i][col=d], validated C/D mapping
#pragma unroll
    for (int r = 0; r < 4; ++r) {
        int r0 = q * 4 + r;
        out[(size_t)(rowbase + r0) * HID + dbase + m]      = acc0[r] * denv[r0];
        out[(size_t)(rowbase + 16 + r0) * HID + dbase + m] = acc1[r] * denv[16 + r0];
    }
}

// ---------------------------------------------------------------------------
extern "C" void kernel_launch(void* const* d_in, const int* in_sizes, int n_in,
                              void* d_out, int out_size, void* d_ws, size_t ws_size,
                              hipStream_t stream) {
    const float* X     = (const float*)d_in[0]; // token_embedding [4,2048,512]
    const float* W     = (const float*)d_in[1]; // fc_w [128,512]
    const float* fcb   = (const float*)d_in[2]; // fc_b [128]
    const float* attnw = (const float*)d_in[3]; // attn_w [1,256]
    const float* attnb = (const float*)d_in[4]; // attn_b [1]
    const float* lng   = (const float*)d_in[5]; // ln_g [128]
    const float* lnb   = (const float*)d_in[6]; // ln_b [128]
    float* out = (float*)d_out;                 // h_prime [4,2048,128] fp32

    char* ws = (char*)d_ws;
    unsigned short* hT   = (unsigned short*)ws;                          // 2 MB
    float*          srow = (float*)(ws + 2u * 1024 * 1024);              // 32 KB
    float*          cchd = (float*)(ws + 2u * 1024 * 1024 + 32u * 1024); // 32 KB

    k_fused<<<NROWS / 16, 512, 0, stream>>>(X, W, fcb, attnw, attnb, lng, lnb,
                                            hT, srow, cchd);
    k_attn <<<NROWS / 32, 512, 0, stream>>>(hT, srow, cchd, out);
}